// Round 10
// baseline (234.035 us; speedup 1.0000x reference)
//
#include <hip/hip_runtime.h>
#include <hip/hip_bf16.h>
#include <math.h>

// ---------------------------------------------------------------------------
// TransformerLayer: B=2 S=2048 D=1024 H=16 HD=64. I/O f32, internals bf16.
// Round 10: attention split-K over keys (KSPLIT=2, grid.z) -> 4 blocks/CU
// occupancy, + merge kernel; 5-bit LDS swizzle (row&7 ^ row>>3&3) kills the
// 4-way read conflicts. GEMMs/LN unchanged from round 9.
// ---------------------------------------------------------------------------

#define B_ 2
#define S_ 2048
#define D_ 1024
#define H_ 16
#define HD_ 64

typedef __bf16 bf16_t;
typedef __bf16 bf16x8 __attribute__((ext_vector_type(8)));
typedef __bf16 bf16x4v __attribute__((ext_vector_type(4)));
typedef float f32x4 __attribute__((ext_vector_type(4)));
typedef float f32x16 __attribute__((ext_vector_type(16)));
typedef unsigned int u32;

__device__ __forceinline__ f32x4 mfma16(bf16x8 a, bf16x8 b, f32x4 c) {
  return __builtin_amdgcn_mfma_f32_16x16x32_bf16(a, b, c, 0, 0, 0);
}
__device__ __forceinline__ f32x16 mfma32(bf16x8 a, bf16x8 b, f32x16 c) {
  return __builtin_amdgcn_mfma_f32_32x32x16_bf16(a, b, c, 0, 0, 0);
}
__device__ __forceinline__ u32 pkbf(float a, float b) {
  union { bf16_t h[2]; u32 u; } t;
  t.h[0] = (bf16_t)a; t.h[1] = (bf16_t)b;
  return t.u;
}

// global -> LDS direct copy, 16B/lane. LDS dest: wave-uniform base + lane*16.
__device__ __forceinline__ void gload_lds16(const bf16_t* g, bf16_t* l) {
  __builtin_amdgcn_global_load_lds((const __attribute__((address_space(1))) void*)g,
                                   (__attribute__((address_space(3))) void*)l,
                                   16, 0, 0);
}

// ---------------------------------------------------------------------------
// Kernel 0: convert 6 f32 weight matrices (D x D) to bf16, contiguous in dst.
// ---------------------------------------------------------------------------
__global__ __launch_bounds__(256) void cvtw_kernel(
    const float* __restrict__ w0, const float* __restrict__ w1,
    const float* __restrict__ w2, const float* __restrict__ w3,
    const float* __restrict__ w4, const float* __restrict__ w5,
    bf16_t* __restrict__ dst) {
  const int wsel = blockIdx.y;
  const float* src = wsel == 0 ? w0 : wsel == 1 ? w1 : wsel == 2 ? w2
                   : wsel == 3 ? w3 : wsel == 4 ? w4 : w5;
  const size_t off = (size_t)blockIdx.x * 1024 + threadIdx.x * 4;
  float4 v = *(const float4*)(src + off);
  bf16x4v r;
  r[0] = (bf16_t)v.x; r[1] = (bf16_t)v.y; r[2] = (bf16_t)v.z; r[3] = (bf16_t)v.w;
  *(bf16x4v*)(dst + (size_t)wsel * (D_ * D_) + off) = r;
}

// ---------------------------------------------------------------------------
// Kernel 1: positional encoding + add; f32 in -> bf16 out (q,k,v one pass).
// ---------------------------------------------------------------------------
__global__ __launch_bounds__(256) void addpe_kernel(
    const float* __restrict__ q, const float* __restrict__ k,
    const float* __restrict__ v,
    bf16_t* __restrict__ qo, bf16_t* __restrict__ ko, bf16_t* __restrict__ vo) {
  const int row = blockIdx.x;            // b*S + s
  const int s = row & (S_ - 1);
  const int d0 = threadIdx.x * 4;
  const size_t base = (size_t)row * D_ + d0;
  float pe[4];
#pragma unroll
  for (int p = 0; p < 2; ++p) {
    float div = __expf((float)(d0 + 2 * p) * -0.008994473019508f);
    float ang = (float)s * div;
    pe[2 * p]     = sinf(ang);
    pe[2 * p + 1] = cosf(ang);
  }
  float4 qv = *(const float4*)&q[base];
  float4 kv = *(const float4*)&k[base];
  float4 vv = *(const float4*)&v[base];
  bf16x4v qr, kr, vr;
  qr[0] = (bf16_t)(qv.x + pe[0]); qr[1] = (bf16_t)(qv.y + pe[1]);
  qr[2] = (bf16_t)(qv.z + pe[2]); qr[3] = (bf16_t)(qv.w + pe[3]);
  kr[0] = (bf16_t)(kv.x + pe[0]); kr[1] = (bf16_t)(kv.y + pe[1]);
  kr[2] = (bf16_t)(kv.z + pe[2]); kr[3] = (bf16_t)(kv.w + pe[3]);
  vr[0] = (bf16_t)(vv.x + pe[0]); vr[1] = (bf16_t)(vv.y + pe[1]);
  vr[2] = (bf16_t)(vv.z + pe[2]); vr[3] = (bf16_t)(vv.w + pe[3]);
  *(bf16x4v*)&qo[base] = qr;
  *(bf16x4v*)&ko[base] = kr;
  *(bf16x4v*)&vo[base] = vr;
}

// ---------------------------------------------------------------------------
// Kernel 2a: singles NT GEMM, tile 128x64 (grid 512 = 2 blocks/CU), BK=32,
// 4 waves (2x2, each 64x32), 2-phase dbuf, all-gload_lds.
// EPI: 0 plain, 1 +bias, 2 +bias+relu
// ---------------------------------------------------------------------------
template <int EPI>
__global__ __launch_bounds__(256) void gemm_s(
    const bf16_t* __restrict__ A, const bf16_t* __restrict__ Wb,
    const float* __restrict__ bias, bf16_t* __restrict__ C) {
  constexpr int Kd = 1024, NT = Kd / 32;
  __shared__ alignas(16) bf16_t As[2][128 * 32];
  __shared__ alignas(16) bf16_t Bs[2][64 * 32];
  const int t = threadIdx.x, lane = t & 63, wid = t >> 6;
  const int m0 = blockIdx.y * 128, n0 = blockIdx.x * 64;

  const bf16_t* Asrc0 = A + (size_t)(m0 + wid * 16 + (lane >> 2)) * Kd + (lane & 3) * 8;
  const bf16_t* Asrc1 = Asrc0 + (size_t)64 * Kd;
  const bf16_t* Wsrc = Wb + (size_t)(n0 + wid * 16 + (lane >> 2)) * Kd + (lane & 3) * 8;

  const f32x4 zero = {0.f, 0.f, 0.f, 0.f};
  f32x4 acc[4][2];
#pragma unroll
  for (int m = 0; m < 4; ++m) { acc[m][0] = zero; acc[m][1] = zero; }

  gload_lds16(Asrc0, &As[0][wid * 512]);
  gload_lds16(Asrc1, &As[0][2048 + wid * 512]);
  gload_lds16(Wsrc,  &Bs[0][wid * 512]);

  const int wr = wid >> 1, wc = wid & 1;
#pragma unroll 2
  for (int kt = 0; kt < NT; ++kt) {
    __syncthreads();
    const int cur = kt & 1, nxt = cur ^ 1;
    if (kt + 1 < NT) {
      const int k0 = (kt + 1) * 32;
      gload_lds16(Asrc0 + k0, &As[nxt][wid * 512]);
      gload_lds16(Asrc1 + k0, &As[nxt][2048 + wid * 512]);
      gload_lds16(Wsrc + k0,  &Bs[nxt][wid * 512]);
    }
    bf16x8 af[4], bfr[2];
#pragma unroll
    for (int m = 0; m < 4; ++m)
      af[m] = *(const bf16x8*)&As[cur][(wr * 64 + m * 16 + (lane & 15)) * 32 + (lane >> 4) * 8];
#pragma unroll
    for (int n = 0; n < 2; ++n)
      bfr[n] = *(const bf16x8*)&Bs[cur][(wc * 32 + n * 16 + (lane & 15)) * 32 + (lane >> 4) * 8];
    __builtin_amdgcn_s_setprio(1);
#pragma unroll
    for (int m = 0; m < 4; ++m)
#pragma unroll
      for (int n = 0; n < 2; ++n)
        acc[m][n] = mfma16(af[m], bfr[n], acc[m][n]);
    __builtin_amdgcn_s_setprio(0);
  }

  const int rbase = m0 + wr * 64 + (lane >> 4) * 4;
  const int cbase = n0 + wc * 32 + (lane & 15);
#pragma unroll
  for (int n = 0; n < 2; ++n) {
    const int col = cbase + n * 16;
    float bv = (EPI >= 1) ? bias[col] : 0.f;
#pragma unroll
    for (int m = 0; m < 4; ++m)
#pragma unroll
      for (int r = 0; r < 4; ++r) {
        float vv = acc[m][n][r] + bv;
        if (EPI == 2) vv = fmaxf(vv, 0.f);
        C[(size_t)(rbase + m * 16 + r) * D_ + col] = (bf16_t)vv;
      }
  }
}

// ---------------------------------------------------------------------------
// Kernel 2b: QKV batched GEMM, tile 128x128 (grid 768 = 3 blocks/CU), BK=32,
// 4 waves (2x2, each 64x64), 2-phase dbuf. z: 0=Q, 1=K, 2=V^T out.
// ---------------------------------------------------------------------------
__global__ __launch_bounds__(256) void gemm_qkv(
    const bf16_t* __restrict__ a0p, const bf16_t* __restrict__ a1p,
    const bf16_t* __restrict__ a2p,
    const bf16_t* __restrict__ w0p, const bf16_t* __restrict__ w1p,
    const bf16_t* __restrict__ w2p,
    bf16_t* __restrict__ o0, bf16_t* __restrict__ o1, bf16_t* __restrict__ o2) {
  constexpr int Kd = 1024, NT = Kd / 32;
  __shared__ alignas(16) bf16_t As[2][128 * 32];
  __shared__ alignas(16) bf16_t Bs[2][128 * 32];
  const int t = threadIdx.x, lane = t & 63, wid = t >> 6;
  const int g = lane >> 4, c16 = lane & 15;
  const int m0 = blockIdx.y * 128, n0 = blockIdx.x * 128;

  const bf16_t* A = a0p;
  const bf16_t* Wb = w0p;
  if (blockIdx.z == 1) { A = a1p; Wb = w1p; }
  else if (blockIdx.z == 2) { A = a2p; Wb = w2p; }

  const bf16_t* Asrc0 = A + (size_t)(m0 + wid * 16 + (lane >> 2)) * Kd + (lane & 3) * 8;
  const bf16_t* Asrc1 = Asrc0 + (size_t)64 * Kd;
  const bf16_t* Wsrc0 = Wb + (size_t)(n0 + wid * 16 + (lane >> 2)) * Kd + (lane & 3) * 8;
  const bf16_t* Wsrc1 = Wsrc0 + (size_t)64 * Kd;

  const f32x4 zero = {0.f, 0.f, 0.f, 0.f};
  f32x4 acc[4][4];
#pragma unroll
  for (int m = 0; m < 4; ++m)
#pragma unroll
    for (int n = 0; n < 4; ++n) acc[m][n] = zero;

  gload_lds16(Asrc0, &As[0][wid * 512]);
  gload_lds16(Asrc1, &As[0][2048 + wid * 512]);
  gload_lds16(Wsrc0, &Bs[0][wid * 512]);
  gload_lds16(Wsrc1, &Bs[0][2048 + wid * 512]);

  const int wr = wid >> 1, wc = wid & 1;
#pragma unroll 2
  for (int kt = 0; kt < NT; ++kt) {
    __syncthreads();
    const int cur = kt & 1, nxt = cur ^ 1;
    if (kt + 1 < NT) {
      const int k0 = (kt + 1) * 32;
      gload_lds16(Asrc0 + k0, &As[nxt][wid * 512]);
      gload_lds16(Asrc1 + k0, &As[nxt][2048 + wid * 512]);
      gload_lds16(Wsrc0 + k0, &Bs[nxt][wid * 512]);
      gload_lds16(Wsrc1 + k0, &Bs[nxt][2048 + wid * 512]);
    }
    bf16x8 af[4], bfr[4];
#pragma unroll
    for (int m = 0; m < 4; ++m)
      af[m] = *(const bf16x8*)&As[cur][(wr * 64 + m * 16 + c16) * 32 + g * 8];
#pragma unroll
    for (int n = 0; n < 4; ++n)
      bfr[n] = *(const bf16x8*)&Bs[cur][(wc * 64 + n * 16 + c16) * 32 + g * 8];
    __builtin_amdgcn_s_setprio(1);
#pragma unroll
    for (int m = 0; m < 4; ++m)
#pragma unroll
      for (int n = 0; n < 4; ++n)
        acc[m][n] = mfma16(af[m], bfr[n], acc[m][n]);
    __builtin_amdgcn_s_setprio(0);
  }

  const int rbase = m0 + wr * 64 + g * 4;
  const int cbase = n0 + wc * 64 + c16;
  if (blockIdx.z == 2) {
#pragma unroll
    for (int n = 0; n < 4; ++n) {
      const int col = cbase + n * 16;
#pragma unroll
      for (int m = 0; m < 4; ++m)
#pragma unroll
        for (int r = 0; r < 4; ++r) {
          const int row = rbase + m * 16 + r;
          const int bb = row >> 11, ss = row & (S_ - 1);
          o2[(size_t)bb * D_ * S_ + (size_t)col * S_ + ss] = (bf16_t)acc[m][n][r];
        }
    }
  } else {
    bf16_t* C = (blockIdx.z == 1) ? o1 : o0;
#pragma unroll
    for (int n = 0; n < 4; ++n) {
      const int col = cbase + n * 16;
#pragma unroll
      for (int m = 0; m < 4; ++m)
#pragma unroll
        for (int r = 0; r < 4; ++r)
          C[(size_t)(rbase + m * 16 + r) * D_ + col] = (bf16_t)acc[m][n][r];
    }
  }
}

// ---------------------------------------------------------------------------
// Kernel 3: flash attention, swapped-operand 32x32 MFMA, lane-local PV,
// split-K over keys: grid (S/128, B*H, 2); split z handles keys
// [z*1024, z*1024+1024), NT=16 tiles. Writes normalized partial O to Op[z]
// and per-row (m, l) to lm. 5-bit swizzle s(row)=(row&7)^((row>>3)&3) makes
// all b128 reads conflict-free. K rows staged swap23-permuted (lane-local P).
// ---------------------------------------------------------------------------
__global__ __launch_bounds__(256) void attn_kernel(
    const bf16_t* __restrict__ Q, const bf16_t* __restrict__ K,
    const bf16_t* __restrict__ Vt, bf16_t* __restrict__ O0,
    bf16_t* __restrict__ O1, float* __restrict__ lm) {
  constexpr int NT = (S_ / 2) / 64;        // 16 key-tiles per split
  constexpr float THR = 11.5416f;          // 8 * log2(e)
  __shared__ alignas(16) bf16_t Ks[2][64 * 64];
  __shared__ alignas(16) bf16_t Vs[2][64 * 64];
  const int t = threadIdx.x, lane = t & 63, wid = t >> 6;
  const int b = blockIdx.y >> 4, h = blockIdx.y & 15;
  const int z = blockIdx.z;
  const int qw = blockIdx.x * 128 + wid * 32;   // this wave's 32 q-rows
  const int q31 = lane & 31, hi = lane >> 5;
  bf16_t* __restrict__ Op = z ? O1 : O0;

  // Q as B-operand frags: col=lane&31=q, k=hi*8+j = d within 16-slice.
  bf16x8 qb[4];
  {
    const size_t qrow = (size_t)(b * S_ + qw + q31) * D_ + h * HD_ + hi * 8;
#pragma unroll
    for (int ksl = 0; ksl < 4; ++ksl) {
      bf16x8 v = *(const bf16x8*)&Q[qrow + ksl * 16];
#pragma unroll
      for (int j = 0; j < 8; ++j)
        v[j] = (bf16_t)((float)v[j] * (0.125f * 1.44269504f));
      qb[ksl] = v;
    }
  }
  bf16x8 onesb;
#pragma unroll
  for (int j = 0; j < 8; ++j) onesb[j] = (bf16_t)1.0f;

  f32x16 ctx0 = {0.f,0.f,0.f,0.f,0.f,0.f,0.f,0.f,0.f,0.f,0.f,0.f,0.f,0.f,0.f,0.f};
  f32x16 ctx1 = ctx0, lf = ctx0;
  float mrow = -1e30f;

  // 5-bit swizzle: logical slot x at row r -> phys (x ^ (r&7) ^ ((r>>3)&3))*8.
  // Rows r and r+32 share the swizzle value.
  const int srow5 = (q31 & 7) ^ ((q31 >> 3) & 3);
  int sw[4];
#pragma unroll
  for (int x = 0; x < 4; ++x) sw[x] = ((x * 2 + hi) ^ srow5) * 8;

  // staging: wave w, chunk c covers LDS tile-rows c*32 + w*8 + (lane>>3);
  // phys slot (lane&7) holds logical slot (lane&7)^s(trow).
  // K global row = swap23(LDS row) + z*1024 (key permutation, algebra-neutral).
  const int trow = wid * 8 + (lane >> 3);
  const int krow_g = (trow & ~12) | ((trow & 4) << 1) | ((trow & 8) >> 1);
  const int st5 = (trow & 7) ^ ((trow >> 3) & 3);
  const int lslot = ((lane & 7) ^ st5) * 8;
  const size_t zoff = (size_t)z * (S_ / 2);
  const bf16_t* Ksrc0 = K + (size_t)(b * S_ + zoff + krow_g) * D_ + h * HD_ + lslot;
  const bf16_t* Ksrc1 = K + (size_t)(b * S_ + zoff + 32 + krow_g) * D_ + h * HD_ + lslot;
  const bf16_t* Vsrc0 = Vt + (size_t)b * D_ * S_ + (size_t)(h * HD_ + trow) * S_ + zoff + lslot;
  const bf16_t* Vsrc1 = Vt + (size_t)b * D_ * S_ + (size_t)(h * HD_ + 32 + trow) * S_ + zoff + lslot;

  gload_lds16(Ksrc0, &Ks[0][wid * 512]);
  gload_lds16(Ksrc1, &Ks[0][2048 + wid * 512]);
  gload_lds16(Vsrc0, &Vs[0][wid * 512]);
  gload_lds16(Vsrc1, &Vs[0][2048 + wid * 512]);

#pragma unroll 2
  for (int kt = 0; kt < NT; ++kt) {
    __syncthreads();                       // tile kt resident
    const int cur = kt & 1, nxt = cur ^ 1;
    if (kt + 1 < NT) {
      const size_t ko = (size_t)(kt + 1) * 64 * D_;
      gload_lds16(Ksrc0 + ko, &Ks[nxt][wid * 512]);
      gload_lds16(Ksrc1 + ko, &Ks[nxt][2048 + wid * 512]);
      const size_t vo = (size_t)(kt + 1) * 64;
      gload_lds16(Vsrc0 + vo, &Vs[nxt][wid * 512]);
      gload_lds16(Vsrc1 + vo, &Vs[nxt][2048 + wid * 512]);
    }

    // QK^T swapped: s0 = keys(LDS rows 0..31), s1 = rows 32..63
    f32x16 s0 = {0.f,0.f,0.f,0.f,0.f,0.f,0.f,0.f,0.f,0.f,0.f,0.f,0.f,0.f,0.f,0.f};
    f32x16 s1 = s0;
    __builtin_amdgcn_s_setprio(1);
#pragma unroll
    for (int ksl = 0; ksl < 4; ++ksl) {
      bf16x8 kb0 = *(const bf16x8*)&Ks[cur][q31 * 64 + sw[ksl]];
      bf16x8 kb1 = *(const bf16x8*)&Ks[cur][(32 + q31) * 64 + sw[ksl]];
      s0 = mfma32(kb0, qb[ksl], s0);
      s1 = mfma32(kb1, qb[ksl], s1);
    }
    __builtin_amdgcn_s_setprio(0);

    // lane-local softmax for q = lane&31 (keys split with partner lane^32)
    float mt = fmaxf(s0[0], s1[0]);
#pragma unroll
    for (int r = 1; r < 16; ++r) mt = fmaxf(mt, fmaxf(s0[r], s1[r]));
    mt = fmaxf(mt, __shfl_xor(mt, 32));
    if (__any(mt > mrow + THR)) {
      float mnew = fmaxf(mrow, mt);
      float scl = exp2f(mrow - mnew);
      mrow = mnew;
#pragma unroll
      for (int r = 0; r < 16; ++r) {
        float sc = __shfl(scl, (r & 3) + 8 * (r >> 2) + 4 * hi);
        ctx0[r] *= sc; ctx1[r] *= sc; lf[r] *= sc;
      }
    }
    // P = exp2(s - m) in place
#pragma unroll
    for (int r = 0; r < 16; ++r) {
      s0[r] = exp2f(s0[r] - mrow);
      s1[r] = exp2f(s1[r] - mrow);
    }

    // PV A-frags, lane-local: pa[ks] = pack of regs 8*(ks&1)..+7 of s0/s1
    bf16x8 pa[4];
#pragma unroll
    for (int ks = 0; ks < 4; ++ks) {
      union { u32 w[4]; bf16x8 v; } u;
      if (ks < 2) {
#pragma unroll
        for (int w = 0; w < 4; ++w)
          u.w[w] = pkbf(s0[(ks & 1) * 8 + 2 * w], s0[(ks & 1) * 8 + 2 * w + 1]);
      } else {
#pragma unroll
        for (int w = 0; w < 4; ++w)
          u.w[w] = pkbf(s1[(ks & 1) * 8 + 2 * w], s1[(ks & 1) * 8 + 2 * w + 1]);
      }
      pa[ks] = u.v;
    }

    // l and PV: rows = q (crow layout), cols = d
    __builtin_amdgcn_s_setprio(1);
#pragma unroll
    for (int ks = 0; ks < 4; ++ks) lf = mfma32(pa[ks], onesb, lf);
#pragma unroll
    for (int ks = 0; ks < 4; ++ks) {
      bf16x8 vb0 = *(const bf16x8*)&Vs[cur][q31 * 64 + sw[ks]];
      bf16x8 vb1 = *(const bf16x8*)&Vs[cur][(32 + q31) * 64 + sw[ks]];
      ctx0 = mfma32(pa[ks], vb0, ctx0);
      ctx1 = mfma32(pa[ks], vb1, ctx1);
    }
    __builtin_amdgcn_s_setprio(0);
  }

  // epilogue: normalized partial O + (m,l) per q-row.
  // ctx D-frag row = q = (r&3)+8*(r>>2)+4*hi, col = d = dchunk*32+(lane&31).
  const size_t lmbase = ((size_t)(z * B_ + b) * H_ + h) * S_ + qw;
  constexpr size_t LOFF = (size_t)2 * B_ * H_ * S_;
#pragma unroll
  for (int r = 0; r < 16; ++r) {
    const int q = (r & 3) + 8 * (r >> 2) + 4 * hi;
    const float mq = __shfl(mrow, q);
    const float inv = 1.f / lf[r];
    const size_t ro = (size_t)(b * S_ + qw + q) * D_ + h * HD_ + q31;
    Op[ro]      = (bf16_t)(ctx0[r] * inv);
    Op[ro + 32] = (bf16_t)(ctx1[r] * inv);
    if (q31 == 0) {
      lm[lmbase + q]        = mq;
      lm[LOFF + lmbase + q] = lf[r];
    }
  }
}

// ---------------------------------------------------------------------------
// Kernel 3b: merge the two key-split partials.
// O = (w0*O0 + w1*O1)/(w0+w1), w_z = exp2(m_z - M) * l_z.
// ---------------------------------------------------------------------------
__global__ __launch_bounds__(256) void merge_kernel(
    const bf16_t* __restrict__ O0, const bf16_t* __restrict__ O1,
    const float* __restrict__ lm, bf16_t* __restrict__ ctx) {
  const int row = blockIdx.x;            // b*S + s
  const int b = row >> 11, s = row & (S_ - 1);
  const int d0 = threadIdx.x * 4;
  const int h = d0 >> 6;
  const size_t base = (size_t)row * D_ + d0;
  constexpr size_t LOFF = (size_t)2 * B_ * H_ * S_;
  const size_t i0 = ((size_t)b * H_ + h) * S_ + s;
  const size_t i1 = ((size_t)(B_ + b) * H_ + h) * S_ + s;
  const float m0 = lm[i0], m1 = lm[i1];
  const float l0 = lm[LOFF + i0], l1 = lm[LOFF + i1];
  const float M = fmaxf(m0, m1);
  float w0 = exp2f(m0 - M) * l0;
  float w1 = exp2f(m1 - M) * l1;
  const float inv = 1.f / (w0 + w1);
  w0 *= inv; w1 *= inv;
  bf16x4v a = *(const bf16x4v*)&O0[base];
  bf16x4v c = *(const bf16x4v*)&O1[base];
  bf16x4v o;
#pragma unroll
  for (int e = 0; e < 4; ++e)
    o[e] = (bf16_t)(w0 * (float)a[e] + w1 * (float)c[e]);
  *(bf16x4v*)&ctx[base] = o;
}

// ---------------------------------------------------------------------------
// Kernel 4: out = LayerNorm(a + res) * g + b.  a,res bf16; g,b f32.
// ---------------------------------------------------------------------------
template <typename OUT>
__global__ __launch_bounds__(256) void add_ln_kernel(
    const bf16_t* __restrict__ a, const bf16_t* __restrict__ res,
    const float* __restrict__ g, const float* __restrict__ be,
    OUT* __restrict__ out) {
  const int t = threadIdx.x;
  const int d0 = t * 4;
  const size_t base = (size_t)blockIdx.x * D_ + d0;
  bf16x4v av = *(const bf16x4v*)&a[base];
  bf16x4v rv = *(const bf16x4v*)&res[base];
  float x[4];
  float s1 = 0.f, s2 = 0.f;
#pragma unroll
  for (int e = 0; e < 4; ++e) {
    x[e] = (float)av[e] + (float)rv[e];
    s1 += x[e];
    s2 += x[e] * x[e];
  }
#pragma unroll
  for (int o = 32; o > 0; o >>= 1) {
    s1 += __shfl_down(s1, o);
    s2 += __shfl_down(s2, o);
  }
  __shared__ float red[8];
  const int lane = t & 63, wid = t >> 6;
  if (lane == 0) { red[wid] = s1; red[4 + wid] = s2; }
  __syncthreads();
  if (t == 0) {
    float t1 = red[0] + red[1] + red[2] + red[3];
    float t2 = red[4] + red[5] + red[6] + red[7];
    float mu = t1 * (1.f / D_);
    float var = t2 * (1.f / D_) - mu * mu;
    red[0] = mu;
    red[1] = rsqrtf(var + 1e-5f);
  }
  __syncthreads();
  const float mu = red[0], rstd = red[1];
  const float4 gv = *(const float4*)&g[d0];
  const float4 bv = *(const float4*)&be[d0];
  float y[4];
  y[0] = (x[0] - mu) * rstd * gv.x + bv.x;
  y[1] = (x[1] - mu) * rstd * gv.y + bv.y;
  y[2] = (x[2] - mu) * rstd * gv.z + bv.z;
  y[3] = (x[3] - mu) * rstd * gv.w + bv.w;
  if constexpr (sizeof(OUT) == 2) {
    bf16x4v o;
    o[0] = (bf16_t)y[0]; o[1] = (bf16_t)y[1]; o[2] = (bf16_t)y[2]; o[3] = (bf16_t)y[3];
    *(bf16x4v*)&out[base] = o;
  } else {
    float4 o = {y[0], y[1], y[2], y[3]};
    *(float4*)&out[base] = o;
  }
}

// ---------------------------------------------------------------------------
extern "C" void kernel_launch(void* const* d_in, const int* in_sizes, int n_in,
                              void* d_out, int out_size, void* d_ws, size_t ws_size,
                              hipStream_t stream) {
  const float* key   = (const float*)d_in[0];
  const float* value = (const float*)d_in[1];
  const float* query = (const float*)d_in[2];
  const float* Wq = (const float*)d_in[3];
  const float* Wk = (const float*)d_in[4];
  const float* Wv = (const float*)d_in[5];
  const float* Wo = (const float*)d_in[6];
  const float* W1 = (const float*)d_in[7];
  const float* b1 = (const float*)d_in[8];
  const float* W2 = (const float*)d_in[9];
  const float* b2 = (const float*)d_in[10];
  const float* g1 = (const float*)d_in[11];
  const float* be1 = (const float*)d_in[12];
  const float* g2 = (const float*)d_in[13];
  const float* be2 = (const float*)d_in[14];
  float* out = (float*)d_out;

  bf16_t* ws = (bf16_t*)d_ws;
  const size_t NB = (size_t)B_ * S_ * D_;  // 4 Mi elems
  bf16_t* qpe = ws + 0 * NB;
  bf16_t* kpe = ws + 1 * NB;
  bf16_t* vpe = ws + 2 * NB;
  bf16_t* Qp  = ws + 3 * NB;
  bf16_t* Kp  = ws + 4 * NB;
  bf16_t* Vt  = ws + 5 * NB;   // [B][D][S] transposed V projection
  bf16_t* Op0 = kpe;  // attn partial 0 (kpe dead after QKV gemm)
  bf16_t* Op1 = vpe;  // attn partial 1 (vpe dead after QKV gemm)
  bf16_t* ctx = kpe;  // merge output (in-place over Op0)
  bf16_t* ao  = vpe;  // Wo output (overwrites Op1 after merge)
  bf16_t* x1  = Qp;   // dead after attention
  bf16_t* hh  = Kp;   // dead after attention
  bf16_t* ff  = Vt;   // dead after attention

  // bf16 weights in d_out [0,12MB); lm scratch at [12,13)MB; final LN
  // overwrites all of d_out at the end.
  bf16_t* wb = (bf16_t*)d_out;
  const size_t WN = (size_t)D_ * D_;
  bf16_t* Wqb = wb + 0 * WN;
  bf16_t* Wkb = wb + 1 * WN;
  bf16_t* Wvb = wb + 2 * WN;
  bf16_t* Wob = wb + 3 * WN;
  bf16_t* W1b = wb + 4 * WN;
  bf16_t* W2b = wb + 5 * WN;
  float* lm = (float*)d_out + 3 * 1024 * 1024;   // after 12MB of weights

  dim3 sgrid(D_ / 64, (B_ * S_) / 128);        // 16 x 32 = 512 (2/CU)

  cvtw_kernel<<<dim3(D_ * D_ / 1024, 6), 256, 0, stream>>>(
      Wq, Wk, Wv, Wo, W1, W2, wb);
  addpe_kernel<<<B_ * S_, 256, 0, stream>>>(query, key, value, qpe, kpe, vpe);

  gemm_qkv<<<dim3(D_ / 128, (B_ * S_) / 128, 3), 256, 0, stream>>>(
      qpe, kpe, vpe, Wqb, Wkb, Wvb, Qp, Kp, Vt);

  attn_kernel<<<dim3(S_ / 128, B_ * H_, 2), 256, 0, stream>>>(
      Qp, Kp, Vt, Op0, Op1, lm);
  merge_kernel<<<B_ * S_, 256, 0, stream>>>(Op0, Op1, lm, ctx);

  gemm_s<0><<<sgrid, 256, 0, stream>>>(ctx, Wob, nullptr, ao);
  add_ln_kernel<bf16_t><<<B_ * S_, 256, 0, stream>>>(ao, qpe, g1, be1, x1);

  gemm_s<2><<<sgrid, 256, 0, stream>>>(x1, W1b, b1, hh);
  gemm_s<1><<<sgrid, 256, 0, stream>>>(hh, W2b, b2, ff);
  add_ln_kernel<float><<<B_ * S_, 256, 0, stream>>>(ff, x1, g2, be2, out);
}

// Round 12
// 211.688 us; speedup vs baseline: 1.1056x; 1.1056x over previous
//
#include <hip/hip_runtime.h>
#include <hip/hip_bf16.h>
#include <math.h>

// ---------------------------------------------------------------------------
// TransformerLayer: B=2 S=2048 D=1024 H=16 HD=64. I/O f32, internals bf16.
// Round 12: r11 minus the gemm_qkv smem-union/V^T-bounce rewrite (reverted to
// r9-proven body + scattered V^T store). Kept: XCD-chunk swizzle on both
// GEMMs, attention 5-bit LDS swizzle + max3 + lane-local PV, vectorized LN.
// ---------------------------------------------------------------------------

#define B_ 2
#define S_ 2048
#define D_ 1024
#define H_ 16
#define HD_ 64

typedef __bf16 bf16_t;
typedef __bf16 bf16x8 __attribute__((ext_vector_type(8)));
typedef __bf16 bf16x4v __attribute__((ext_vector_type(4)));
typedef float f32x4 __attribute__((ext_vector_type(4)));
typedef float f32x16 __attribute__((ext_vector_type(16)));
typedef unsigned int u32;

__device__ __forceinline__ f32x4 mfma16(bf16x8 a, bf16x8 b, f32x4 c) {
  return __builtin_amdgcn_mfma_f32_16x16x32_bf16(a, b, c, 0, 0, 0);
}
__device__ __forceinline__ f32x16 mfma32(bf16x8 a, bf16x8 b, f32x16 c) {
  return __builtin_amdgcn_mfma_f32_32x32x16_bf16(a, b, c, 0, 0, 0);
}
__device__ __forceinline__ u32 pkbf(float a, float b) {
  union { bf16_t h[2]; u32 u; } t;
  t.h[0] = (bf16_t)a; t.h[1] = (bf16_t)b;
  return t.u;
}

// global -> LDS direct copy, 16B/lane. LDS dest: wave-uniform base + lane*16.
__device__ __forceinline__ void gload_lds16(const bf16_t* g, bf16_t* l) {
  __builtin_amdgcn_global_load_lds((const __attribute__((address_space(1))) void*)g,
                                   (__attribute__((address_space(3))) void*)l,
                                   16, 0, 0);
}

// ---------------------------------------------------------------------------
// Kernel 0: convert 6 f32 weight matrices (D x D) to bf16, contiguous in dst.
// ---------------------------------------------------------------------------
__global__ __launch_bounds__(256) void cvtw_kernel(
    const float* __restrict__ w0, const float* __restrict__ w1,
    const float* __restrict__ w2, const float* __restrict__ w3,
    const float* __restrict__ w4, const float* __restrict__ w5,
    bf16_t* __restrict__ dst) {
  const int wsel = blockIdx.y;
  const float* src = wsel == 0 ? w0 : wsel == 1 ? w1 : wsel == 2 ? w2
                   : wsel == 3 ? w3 : wsel == 4 ? w4 : w5;
  const size_t off = (size_t)blockIdx.x * 1024 + threadIdx.x * 4;
  float4 v = *(const float4*)(src + off);
  bf16x4v r;
  r[0] = (bf16_t)v.x; r[1] = (bf16_t)v.y; r[2] = (bf16_t)v.z; r[3] = (bf16_t)v.w;
  *(bf16x4v*)(dst + (size_t)wsel * (D_ * D_) + off) = r;
}

// ---------------------------------------------------------------------------
// Kernel 1: positional encoding + add; f32 in -> bf16 out (q,k,v one pass).
// ---------------------------------------------------------------------------
__global__ __launch_bounds__(256) void addpe_kernel(
    const float* __restrict__ q, const float* __restrict__ k,
    const float* __restrict__ v,
    bf16_t* __restrict__ qo, bf16_t* __restrict__ ko, bf16_t* __restrict__ vo) {
  const int row = blockIdx.x;            // b*S + s
  const int s = row & (S_ - 1);
  const int d0 = threadIdx.x * 4;
  const size_t base = (size_t)row * D_ + d0;
  float pe[4];
#pragma unroll
  for (int p = 0; p < 2; ++p) {
    float div = __expf((float)(d0 + 2 * p) * -0.008994473019508f);
    float ang = (float)s * div;
    pe[2 * p]     = sinf(ang);
    pe[2 * p + 1] = cosf(ang);
  }
  float4 qv = *(const float4*)&q[base];
  float4 kv = *(const float4*)&k[base];
  float4 vv = *(const float4*)&v[base];
  bf16x4v qr, kr, vr;
  qr[0] = (bf16_t)(qv.x + pe[0]); qr[1] = (bf16_t)(qv.y + pe[1]);
  qr[2] = (bf16_t)(qv.z + pe[2]); qr[3] = (bf16_t)(qv.w + pe[3]);
  kr[0] = (bf16_t)(kv.x + pe[0]); kr[1] = (bf16_t)(kv.y + pe[1]);
  kr[2] = (bf16_t)(kv.z + pe[2]); kr[3] = (bf16_t)(kv.w + pe[3]);
  vr[0] = (bf16_t)(vv.x + pe[0]); vr[1] = (bf16_t)(vv.y + pe[1]);
  vr[2] = (bf16_t)(vv.z + pe[2]); vr[3] = (bf16_t)(vv.w + pe[3]);
  *(bf16x4v*)&qo[base] = qr;
  *(bf16x4v*)&ko[base] = kr;
  *(bf16x4v*)&vo[base] = vr;
}

// ---------------------------------------------------------------------------
// Kernel 2a: singles NT GEMM, tile 128x64 (512 blocks, XCD-chunk swizzled),
// BK=32, 4 waves (2x2, each 64x32), 2-phase dbuf, all-gload_lds.
// EPI: 0 plain, 1 +bias, 2 +bias+relu
// ---------------------------------------------------------------------------
template <int EPI>
__global__ __launch_bounds__(256) void gemm_s(
    const bf16_t* __restrict__ A, const bf16_t* __restrict__ Wb,
    const float* __restrict__ bias, bf16_t* __restrict__ C) {
  constexpr int Kd = 1024, NT = Kd / 32;
  __shared__ alignas(16) bf16_t As[2][128 * 32];
  __shared__ alignas(16) bf16_t Bs[2][64 * 32];
  const int t = threadIdx.x, lane = t & 63, wid = t >> 6;
  // XCD-chunk swizzle (m204, nwg%8==0): 512 blocks = 8 XCDs x 64.
  const int bid = blockIdx.y * 16 + blockIdx.x;
  const int virt = (bid & 7) * 64 + (bid >> 3);
  const int m0 = (virt >> 4) * 128, n0 = (virt & 15) * 64;

  const bf16_t* Asrc0 = A + (size_t)(m0 + wid * 16 + (lane >> 2)) * Kd + (lane & 3) * 8;
  const bf16_t* Asrc1 = Asrc0 + (size_t)64 * Kd;
  const bf16_t* Wsrc = Wb + (size_t)(n0 + wid * 16 + (lane >> 2)) * Kd + (lane & 3) * 8;

  const f32x4 zero = {0.f, 0.f, 0.f, 0.f};
  f32x4 acc[4][2];
#pragma unroll
  for (int m = 0; m < 4; ++m) { acc[m][0] = zero; acc[m][1] = zero; }

  gload_lds16(Asrc0, &As[0][wid * 512]);
  gload_lds16(Asrc1, &As[0][2048 + wid * 512]);
  gload_lds16(Wsrc,  &Bs[0][wid * 512]);

  const int wr = wid >> 1, wc = wid & 1;
#pragma unroll 2
  for (int kt = 0; kt < NT; ++kt) {
    __syncthreads();
    const int cur = kt & 1, nxt = cur ^ 1;
    if (kt + 1 < NT) {
      const int k0 = (kt + 1) * 32;
      gload_lds16(Asrc0 + k0, &As[nxt][wid * 512]);
      gload_lds16(Asrc1 + k0, &As[nxt][2048 + wid * 512]);
      gload_lds16(Wsrc + k0,  &Bs[nxt][wid * 512]);
    }
    bf16x8 af[4], bfr[2];
#pragma unroll
    for (int m = 0; m < 4; ++m)
      af[m] = *(const bf16x8*)&As[cur][(wr * 64 + m * 16 + (lane & 15)) * 32 + (lane >> 4) * 8];
#pragma unroll
    for (int n = 0; n < 2; ++n)
      bfr[n] = *(const bf16x8*)&Bs[cur][(wc * 32 + n * 16 + (lane & 15)) * 32 + (lane >> 4) * 8];
    __builtin_amdgcn_s_setprio(1);
#pragma unroll
    for (int m = 0; m < 4; ++m)
#pragma unroll
      for (int n = 0; n < 2; ++n)
        acc[m][n] = mfma16(af[m], bfr[n], acc[m][n]);
    __builtin_amdgcn_s_setprio(0);
  }

  const int rbase = m0 + wr * 64 + (lane >> 4) * 4;
  const int cbase = n0 + wc * 32 + (lane & 15);
#pragma unroll
  for (int n = 0; n < 2; ++n) {
    const int col = cbase + n * 16;
    float bv = (EPI >= 1) ? bias[col] : 0.f;
#pragma unroll
    for (int m = 0; m < 4; ++m)
#pragma unroll
      for (int r = 0; r < 4; ++r) {
        float vv = acc[m][n][r] + bv;
        if (EPI == 2) vv = fmaxf(vv, 0.f);
        C[(size_t)(rbase + m * 16 + r) * D_ + col] = (bf16_t)vv;
      }
  }
}

// ---------------------------------------------------------------------------
// Kernel 2b: QKV batched GEMM, tile 128x128 (768 blocks, XCD-chunk swizzled),
// BK=32, 4 waves (2x2, each 64x64), 2-phase dbuf. r9-proven body.
// virt z: 0=Q, 1=K, 2=V^T out (scattered store).
// ---------------------------------------------------------------------------
__global__ __launch_bounds__(256) void gemm_qkv(
    const bf16_t* __restrict__ a0p, const bf16_t* __restrict__ a1p,
    const bf16_t* __restrict__ a2p,
    const bf16_t* __restrict__ w0p, const bf16_t* __restrict__ w1p,
    const bf16_t* __restrict__ w2p,
    bf16_t* __restrict__ o0, bf16_t* __restrict__ o1, bf16_t* __restrict__ o2) {
  constexpr int Kd = 1024, NT = Kd / 32;
  __shared__ alignas(16) bf16_t As[2][128 * 32];
  __shared__ alignas(16) bf16_t Bs[2][128 * 32];
  const int t = threadIdx.x, lane = t & 63, wid = t >> 6;
  const int g = lane >> 4, c16 = lane & 15;
  // XCD-chunk swizzle (m204, nwg%8==0): 768 blocks = 8 XCDs x 96.
  const int bid = blockIdx.z * 256 + blockIdx.y * 8 + blockIdx.x;
  const int virt = (bid & 7) * 96 + (bid >> 3);
  const int zz = virt >> 8;
  const int m0 = ((virt >> 3) & 31) * 128, n0 = (virt & 7) * 128;

  const bf16_t* A = a0p;
  const bf16_t* Wb = w0p;
  if (zz == 1) { A = a1p; Wb = w1p; }
  else if (zz == 2) { A = a2p; Wb = w2p; }

  const bf16_t* Asrc0 = A + (size_t)(m0 + wid * 16 + (lane >> 2)) * Kd + (lane & 3) * 8;
  const bf16_t* Asrc1 = Asrc0 + (size_t)64 * Kd;
  const bf16_t* Wsrc0 = Wb + (size_t)(n0 + wid * 16 + (lane >> 2)) * Kd + (lane & 3) * 8;
  const bf16_t* Wsrc1 = Wsrc0 + (size_t)64 * Kd;

  const f32x4 zero = {0.f, 0.f, 0.f, 0.f};
  f32x4 acc[4][4];
#pragma unroll
  for (int m = 0; m < 4; ++m)
#pragma unroll
    for (int n = 0; n < 4; ++n) acc[m][n] = zero;

  gload_lds16(Asrc0, &As[0][wid * 512]);
  gload_lds16(Asrc1, &As[0][2048 + wid * 512]);
  gload_lds16(Wsrc0, &Bs[0][wid * 512]);
  gload_lds16(Wsrc1, &Bs[0][2048 + wid * 512]);

  const int wr = wid >> 1, wc = wid & 1;
#pragma unroll 2
  for (int kt = 0; kt < NT; ++kt) {
    __syncthreads();
    const int cur = kt & 1, nxt = cur ^ 1;
    if (kt + 1 < NT) {
      const int k0 = (kt + 1) * 32;
      gload_lds16(Asrc0 + k0, &As[nxt][wid * 512]);
      gload_lds16(Asrc1 + k0, &As[nxt][2048 + wid * 512]);
      gload_lds16(Wsrc0 + k0, &Bs[nxt][wid * 512]);
      gload_lds16(Wsrc1 + k0, &Bs[nxt][2048 + wid * 512]);
    }
    bf16x8 af[4], bfr[4];
#pragma unroll
    for (int m = 0; m < 4; ++m)
      af[m] = *(const bf16x8*)&As[cur][(wr * 64 + m * 16 + c16) * 32 + g * 8];
#pragma unroll
    for (int n = 0; n < 4; ++n)
      bfr[n] = *(const bf16x8*)&Bs[cur][(wc * 64 + n * 16 + c16) * 32 + g * 8];
    __builtin_amdgcn_s_setprio(1);
#pragma unroll
    for (int m = 0; m < 4; ++m)
#pragma unroll
      for (int n = 0; n < 4; ++n)
        acc[m][n] = mfma16(af[m], bfr[n], acc[m][n]);
    __builtin_amdgcn_s_setprio(0);
  }

  const int rbase = m0 + wr * 64 + g * 4;
  const int cbase = n0 + wc * 64 + c16;
  if (zz == 2) {
#pragma unroll
    for (int n = 0; n < 4; ++n) {
      const int col = cbase + n * 16;
#pragma unroll
      for (int m = 0; m < 4; ++m)
#pragma unroll
        for (int r = 0; r < 4; ++r) {
          const int row = rbase + m * 16 + r;
          const int bb = row >> 11, ss = row & (S_ - 1);
          o2[(size_t)bb * D_ * S_ + (size_t)col * S_ + ss] = (bf16_t)acc[m][n][r];
        }
    }
  } else {
    bf16_t* C = (zz == 1) ? o1 : o0;
#pragma unroll
    for (int n = 0; n < 4; ++n) {
      const int col = cbase + n * 16;
#pragma unroll
      for (int m = 0; m < 4; ++m)
#pragma unroll
        for (int r = 0; r < 4; ++r)
          C[(size_t)(rbase + m * 16 + r) * D_ + col] = (bf16_t)acc[m][n][r];
    }
  }
}

// ---------------------------------------------------------------------------
// Kernel 3: flash attention, swapped-operand 32x32 MFMA, lane-local PV.
// grid (S/128, B*H), 4 waves x 32 q-rows, KVBLK=64, NT=32.
// K staged swap23-row-permuted (lane-local P); 5-bit swizzle
// s(row)=(row&7)^((row>>3)&3) -> all b128 LDS reads conflict-free.
// Softmax lane-local (max3 chain + 1 shfl_xor); l via mfma-ones.
// ---------------------------------------------------------------------------
__global__ __launch_bounds__(256) void attn_kernel(
    const bf16_t* __restrict__ Q, const bf16_t* __restrict__ K,
    const bf16_t* __restrict__ Vt, bf16_t* __restrict__ O) {
  constexpr int NT = S_ / 64;
  constexpr float THR = 11.5416f;          // 8 * log2(e)
  __shared__ alignas(16) bf16_t Ks[2][64 * 64];
  __shared__ alignas(16) bf16_t Vs[2][64 * 64];
  const int t = threadIdx.x, lane = t & 63, wid = t >> 6;
  const int b = blockIdx.y >> 4, h = blockIdx.y & 15;
  const int qw = blockIdx.x * 128 + wid * 32;   // this wave's 32 q-rows
  const int q31 = lane & 31, hi = lane >> 5;

  // Q as B-operand frags: col=lane&31=q, k=hi*8+j = d within 16-slice.
  bf16x8 qb[4];
  {
    const size_t qrow = (size_t)(b * S_ + qw + q31) * D_ + h * HD_ + hi * 8;
#pragma unroll
    for (int ksl = 0; ksl < 4; ++ksl) {
      bf16x8 v = *(const bf16x8*)&Q[qrow + ksl * 16];
#pragma unroll
      for (int j = 0; j < 8; ++j)
        v[j] = (bf16_t)((float)v[j] * (0.125f * 1.44269504f));
      qb[ksl] = v;
    }
  }
  bf16x8 onesb;
#pragma unroll
  for (int j = 0; j < 8; ++j) onesb[j] = (bf16_t)1.0f;

  f32x16 ctx0 = {0.f,0.f,0.f,0.f,0.f,0.f,0.f,0.f,0.f,0.f,0.f,0.f,0.f,0.f,0.f,0.f};
  f32x16 ctx1 = ctx0, lf = ctx0;
  float mrow = -1e30f;

  // 5-bit swizzle: logical slot x at row r -> phys (x ^ (r&7) ^ ((r>>3)&3))*8.
  // Rows r and r+32 share the swizzle value.
  const int srow5 = (q31 & 7) ^ ((q31 >> 3) & 3);
  int sw[4];
#pragma unroll
  for (int x = 0; x < 4; ++x) sw[x] = ((x * 2 + hi) ^ srow5) * 8;

  // staging: wave w, chunk c covers LDS tile-rows c*32 + w*8 + (lane>>3);
  // phys slot (lane&7) holds logical slot (lane&7)^s(trow).
  // K global row = swap23(LDS row) (key permutation, algebra-neutral).
  const int trow = wid * 8 + (lane >> 3);
  const int krow_g = (trow & ~12) | ((trow & 4) << 1) | ((trow & 8) >> 1);
  const int st5 = (trow & 7) ^ ((trow >> 3) & 3);
  const int lslot = ((lane & 7) ^ st5) * 8;
  const bf16_t* Ksrc0 = K + (size_t)(b * S_ + krow_g) * D_ + h * HD_ + lslot;
  const bf16_t* Ksrc1 = K + (size_t)(b * S_ + 32 + krow_g) * D_ + h * HD_ + lslot;
  const bf16_t* Vsrc0 = Vt + (size_t)b * D_ * S_ + (size_t)(h * HD_ + trow) * S_ + lslot;
  const bf16_t* Vsrc1 = Vt + (size_t)b * D_ * S_ + (size_t)(h * HD_ + 32 + trow) * S_ + lslot;

  gload_lds16(Ksrc0, &Ks[0][wid * 512]);
  gload_lds16(Ksrc1, &Ks[0][2048 + wid * 512]);
  gload_lds16(Vsrc0, &Vs[0][wid * 512]);
  gload_lds16(Vsrc1, &Vs[0][2048 + wid * 512]);

#pragma unroll 2
  for (int kt = 0; kt < NT; ++kt) {
    __syncthreads();                       // tile kt resident
    const int cur = kt & 1, nxt = cur ^ 1;
    if (kt + 1 < NT) {
      const size_t ko = (size_t)(kt + 1) * 64 * D_;
      gload_lds16(Ksrc0 + ko, &Ks[nxt][wid * 512]);
      gload_lds16(Ksrc1 + ko, &Ks[nxt][2048 + wid * 512]);
      const size_t vo = (size_t)(kt + 1) * 64;
      gload_lds16(Vsrc0 + vo, &Vs[nxt][wid * 512]);
      gload_lds16(Vsrc1 + vo, &Vs[nxt][2048 + wid * 512]);
    }

    // QK^T swapped: s0 = keys(LDS rows 0..31), s1 = rows 32..63
    f32x16 s0 = {0.f,0.f,0.f,0.f,0.f,0.f,0.f,0.f,0.f,0.f,0.f,0.f,0.f,0.f,0.f,0.f};
    f32x16 s1 = s0;
    __builtin_amdgcn_s_setprio(1);
#pragma unroll
    for (int ksl = 0; ksl < 4; ++ksl) {
      bf16x8 kb0 = *(const bf16x8*)&Ks[cur][q31 * 64 + sw[ksl]];
      bf16x8 kb1 = *(const bf16x8*)&Ks[cur][(32 + q31) * 64 + sw[ksl]];
      s0 = mfma32(kb0, qb[ksl], s0);
      s1 = mfma32(kb1, qb[ksl], s1);
    }
    __builtin_amdgcn_s_setprio(0);

    // lane-local softmax for q = lane&31 (max3-friendly chain)
    float mt = fmaxf(s0[0], s1[0]);
#pragma unroll
    for (int r = 1; r < 16; ++r) mt = fmaxf(fmaxf(mt, s0[r]), s1[r]);
    mt = fmaxf(mt, __shfl_xor(mt, 32));
    if (__any(mt > mrow + THR)) {
      float mnew = fmaxf(mrow, mt);
      float scl = exp2f(mrow - mnew);
      mrow = mnew;
#pragma unroll
      for (int r = 0; r < 16; ++r) {
        float sc = __shfl(scl, (r & 3) + 8 * (r >> 2) + 4 * hi);
        ctx0[r] *= sc; ctx1[r] *= sc; lf[r] *= sc;
      }
    }
    // P = exp2(s - m) in place
#pragma unroll
    for (int r = 0; r < 16; ++r) {
      s0[r] = exp2f(s0[r] - mrow);
      s1[r] = exp2f(s1[r] - mrow);
    }

    // PV A-frags, lane-local: pa[ks] = pack of regs 8*(ks&1)..+7 of s0/s1
    bf16x8 pa[4];
#pragma unroll
    for (int ks = 0; ks < 4; ++ks) {
      union { u32 w[4]; bf16x8 v; } u;
      if (ks < 2) {
#pragma unroll
        for (int w = 0; w < 4; ++w)
          u.w[w] = pkbf(s0[(ks & 1) * 8 + 2 * w], s0[(ks & 1) * 8 + 2 * w + 1]);
      } else {
#pragma unroll
        for (int w = 0; w < 4; ++w)
          u.w[w] = pkbf(s1[(ks & 1) * 8 + 2 * w], s1[(ks & 1) * 8 + 2 * w + 1]);
      }
      pa[ks] = u.v;
    }

    // l and PV: rows = q (crow layout), cols = d
    __builtin_amdgcn_s_setprio(1);
#pragma unroll
    for (int ks = 0; ks < 4; ++ks) lf = mfma32(pa[ks], onesb, lf);
#pragma unroll
    for (int ks = 0; ks < 4; ++ks) {
      bf16x8 vb0 = *(const bf16x8*)&Vs[cur][q31 * 64 + sw[ks]];
      bf16x8 vb1 = *(const bf16x8*)&Vs[cur][(32 + q31) * 64 + sw[ks]];
      ctx0 = mfma32(pa[ks], vb0, ctx0);
      ctx1 = mfma32(pa[ks], vb1, ctx1);
    }
    __builtin_amdgcn_s_setprio(0);
  }

  // epilogue: ctx D-frag row = q = crow(reg,hi), col = d = dchunk*32+(lane&31)
#pragma unroll
  for (int r = 0; r < 16; ++r) {
    const int q = (r & 3) + 8 * (r >> 2) + 4 * hi;
    const float inv = 1.f / lf[r];
    const size_t ro = (size_t)(b * S_ + qw + q) * D_ + h * HD_ + q31;
    O[ro]      = (bf16_t)(ctx0[r] * inv);
    O[ro + 32] = (bf16_t)(ctx1[r] * inv);
  }
}

// ---------------------------------------------------------------------------
// Kernel 4: out = LayerNorm(a + res) * g + b.  a,res bf16; g,b f32.
// ---------------------------------------------------------------------------
template <typename OUT>
__global__ __launch_bounds__(256) void add_ln_kernel(
    const bf16_t* __restrict__ a, const bf16_t* __restrict__ res,
    const float* __restrict__ g, const float* __restrict__ be,
    OUT* __restrict__ out) {
  const int t = threadIdx.x;
  const int d0 = t * 4;
  const size_t base = (size_t)blockIdx.x * D_ + d0;
  bf16x4v av = *(const bf16x4v*)&a[base];
  bf16x4v rv = *(const bf16x4v*)&res[base];
  float x[4];
  float s1 = 0.f, s2 = 0.f;
#pragma unroll
  for (int e = 0; e < 4; ++e) {
    x[e] = (float)av[e] + (float)rv[e];
    s1 += x[e];
    s2 += x[e] * x[e];
  }
#pragma unroll
  for (int o = 32; o > 0; o >>= 1) {
    s1 += __shfl_down(s1, o);
    s2 += __shfl_down(s2, o);
  }
  __shared__ float red[8];
  const int lane = t & 63, wid = t >> 6;
  if (lane == 0) { red[wid] = s1; red[4 + wid] = s2; }
  __syncthreads();
  if (t == 0) {
    float t1 = red[0] + red[1] + red[2] + red[3];
    float t2 = red[4] + red[5] + red[6] + red[7];
    float mu = t1 * (1.f / D_);
    float var = t2 * (1.f / D_) - mu * mu;
    red[0] = mu;
    red[1] = rsqrtf(var + 1e-5f);
  }
  __syncthreads();
  const float mu = red[0], rstd = red[1];
  const float4 gv = *(const float4*)&g[d0];
  const float4 bv = *(const float4*)&be[d0];
  float y[4];
  y[0] = (x[0] - mu) * rstd * gv.x + bv.x;
  y[1] = (x[1] - mu) * rstd * gv.y + bv.y;
  y[2] = (x[2] - mu) * rstd * gv.z + bv.z;
  y[3] = (x[3] - mu) * rstd * gv.w + bv.w;
  if constexpr (sizeof(OUT) == 2) {
    bf16x4v o;
    o[0] = (bf16_t)y[0]; o[1] = (bf16_t)y[1]; o[2] = (bf16_t)y[2]; o[3] = (bf16_t)y[3];
    *(bf16x4v*)&out[base] = o;
  } else {
    float4 o = {y[0], y[1], y[2], y[3]};
    *(float4*)&out[base] = o;
  }
}

// ---------------------------------------------------------------------------
extern "C" void kernel_launch(void* const* d_in, const int* in_sizes, int n_in,
                              void* d_out, int out_size, void* d_ws, size_t ws_size,
                              hipStream_t stream) {
  const float* key   = (const float*)d_in[0];
  const float* value = (const float*)d_in[1];
  const float* query = (const float*)d_in[2];
  const float* Wq = (const float*)d_in[3];
  const float* Wk = (const float*)d_in[4];
  const float* Wv = (const float*)d_in[5];
  const float* Wo = (const float*)d_in[6];
  const float* W1 = (const float*)d_in[7];
  const float* b1 = (const float*)d_in[8];
  const float* W2 = (const float*)d_in[9];
  const float* b2 = (const float*)d_in[10];
  const float* g1 = (const float*)d_in[11];
  const float* be1 = (const float*)d_in[12];
  const float* g2 = (const float*)d_in[13];
  const float* be2 = (const float*)d_in[14];
  float* out = (float*)d_out;

  bf16_t* ws = (bf16_t*)d_ws;
  const size_t NB = (size_t)B_ * S_ * D_;  // 4 Mi elems
  bf16_t* qpe = ws + 0 * NB;
  bf16_t* kpe = ws + 1 * NB;
  bf16_t* vpe = ws + 2 * NB;
  bf16_t* Qp  = ws + 3 * NB;
  bf16_t* Kp  = ws + 4 * NB;
  bf16_t* Vt  = ws + 5 * NB;   // [B][D][S] transposed V projection
  bf16_t* ctx = kpe;  // dead after QKV gemm
  bf16_t* ao  = vpe;  // dead after QKV gemm
  bf16_t* x1  = Qp;   // dead after attention
  bf16_t* hh  = Kp;   // dead after attention
  bf16_t* ff  = Vt;   // dead after attention

  // bf16 weights live in d_out (16 MB; 6 x 2 MB used, overwritten by final LN)
  bf16_t* wb = (bf16_t*)d_out;
  const size_t WN = (size_t)D_ * D_;
  bf16_t* Wqb = wb + 0 * WN;
  bf16_t* Wkb = wb + 1 * WN;
  bf16_t* Wvb = wb + 2 * WN;
  bf16_t* Wob = wb + 3 * WN;
  bf16_t* W1b = wb + 4 * WN;
  bf16_t* W2b = wb + 5 * WN;

  dim3 sgrid(16, 32);                          // 512 blocks (swizzled in-kernel)

  cvtw_kernel<<<dim3(D_ * D_ / 1024, 6), 256, 0, stream>>>(
      Wq, Wk, Wv, Wo, W1, W2, wb);
  addpe_kernel<<<B_ * S_, 256, 0, stream>>>(query, key, value, qpe, kpe, vpe);

  gemm_qkv<<<dim3(8, 32, 3), 256, 0, stream>>>(
      qpe, kpe, vpe, Wqb, Wkb, Wvb, Qp, Kp, Vt);

  attn_kernel<<<dim3(S_ / 128, B_ * H_), 256, 0, stream>>>(Qp, Kp, Vt, ctx);

  gemm_s<0><<<sgrid, 256, 0, stream>>>(ctx, Wob, nullptr, ao);
  add_ln_kernel<bf16_t><<<B_ * S_, 256, 0, stream>>>(ao, qpe, g1, be1, x1);

  gemm_s<2><<<sgrid, 256, 0, stream>>>(x1, W1b, b1, hh);
  gemm_s<1><<<sgrid, 256, 0, stream>>>(hh, W2b, b2, ff);
  add_ln_kernel<float><<<B_ * S_, 256, 0, stream>>>(ff, x1, g2, be2, out);
}

// Round 13
// 199.613 us; speedup vs baseline: 1.1724x; 1.0605x over previous
//
#include <hip/hip_runtime.h>
#include <hip/hip_bf16.h>
#include <math.h>

// ---------------------------------------------------------------------------
// TransformerLayer: B=2 S=2048 D=1024 H=16 HD=64. I/O f32, internals bf16.
// Round 13: (1) attention exp via __builtin_amdgcn_exp2f (1 instr, was libm);
// (2) addpe trig via v_sin/v_cos builtins (revolutions + fract);
// (3) attention KVBLK=128 = two proven 64-key subtiles per barrier (NT=16).
// ---------------------------------------------------------------------------

#define B_ 2
#define S_ 2048
#define D_ 1024
#define H_ 16
#define HD_ 64

typedef __bf16 bf16_t;
typedef __bf16 bf16x8 __attribute__((ext_vector_type(8)));
typedef __bf16 bf16x4v __attribute__((ext_vector_type(4)));
typedef float f32x4 __attribute__((ext_vector_type(4)));
typedef float f32x16 __attribute__((ext_vector_type(16)));
typedef unsigned int u32;

__device__ __forceinline__ f32x4 mfma16(bf16x8 a, bf16x8 b, f32x4 c) {
  return __builtin_amdgcn_mfma_f32_16x16x32_bf16(a, b, c, 0, 0, 0);
}
__device__ __forceinline__ f32x16 mfma32(bf16x8 a, bf16x8 b, f32x16 c) {
  return __builtin_amdgcn_mfma_f32_32x32x16_bf16(a, b, c, 0, 0, 0);
}
__device__ __forceinline__ u32 pkbf(float a, float b) {
  union { bf16_t h[2]; u32 u; } t;
  t.h[0] = (bf16_t)a; t.h[1] = (bf16_t)b;
  return t.u;
}
__device__ __forceinline__ float fexp2(float x) {       // single v_exp_f32
  return __builtin_amdgcn_exp2f(x);
}

// global -> LDS direct copy, 16B/lane. LDS dest: wave-uniform base + lane*16.
__device__ __forceinline__ void gload_lds16(const bf16_t* g, bf16_t* l) {
  __builtin_amdgcn_global_load_lds((const __attribute__((address_space(1))) void*)g,
                                   (__attribute__((address_space(3))) void*)l,
                                   16, 0, 0);
}

// ---------------------------------------------------------------------------
// Kernel 0: convert 6 f32 weight matrices (D x D) to bf16, contiguous in dst.
// ---------------------------------------------------------------------------
__global__ __launch_bounds__(256) void cvtw_kernel(
    const float* __restrict__ w0, const float* __restrict__ w1,
    const float* __restrict__ w2, const float* __restrict__ w3,
    const float* __restrict__ w4, const float* __restrict__ w5,
    bf16_t* __restrict__ dst) {
  const int wsel = blockIdx.y;
  const float* src = wsel == 0 ? w0 : wsel == 1 ? w1 : wsel == 2 ? w2
                   : wsel == 3 ? w3 : wsel == 4 ? w4 : w5;
  const size_t off = (size_t)blockIdx.x * 1024 + threadIdx.x * 4;
  float4 v = *(const float4*)(src + off);
  bf16x4v r;
  r[0] = (bf16_t)v.x; r[1] = (bf16_t)v.y; r[2] = (bf16_t)v.z; r[3] = (bf16_t)v.w;
  *(bf16x4v*)(dst + (size_t)wsel * (D_ * D_) + off) = r;
}

// ---------------------------------------------------------------------------
// Kernel 1: positional encoding + add; f32 in -> bf16 out (q,k,v one pass).
// Trig via v_sin/v_cos (revolutions domain + fract range reduction).
// ---------------------------------------------------------------------------
__global__ __launch_bounds__(256) void addpe_kernel(
    const float* __restrict__ q, const float* __restrict__ k,
    const float* __restrict__ v,
    bf16_t* __restrict__ qo, bf16_t* __restrict__ ko, bf16_t* __restrict__ vo) {
  const int row = blockIdx.x;            // b*S + s
  const int s = row & (S_ - 1);
  const int d0 = threadIdx.x * 4;
  const size_t base = (size_t)row * D_ + d0;
  float pe[4];
#pragma unroll
  for (int p = 0; p < 2; ++p) {
    float div = __expf((float)(d0 + 2 * p) * -0.008994473019508f);
    float rev = (float)s * div * 0.15915494309189535f;   // ang / (2*pi)
    float rf = rev - floorf(rev);
    pe[2 * p]     = __builtin_amdgcn_sinf(rf);
    pe[2 * p + 1] = __builtin_amdgcn_cosf(rf);
  }
  float4 qv = *(const float4*)&q[base];
  float4 kv = *(const float4*)&k[base];
  float4 vv = *(const float4*)&v[base];
  bf16x4v qr, kr, vr;
  qr[0] = (bf16_t)(qv.x + pe[0]); qr[1] = (bf16_t)(qv.y + pe[1]);
  qr[2] = (bf16_t)(qv.z + pe[2]); qr[3] = (bf16_t)(qv.w + pe[3]);
  kr[0] = (bf16_t)(kv.x + pe[0]); kr[1] = (bf16_t)(kv.y + pe[1]);
  kr[2] = (bf16_t)(kv.z + pe[2]); kr[3] = (bf16_t)(kv.w + pe[3]);
  vr[0] = (bf16_t)(vv.x + pe[0]); vr[1] = (bf16_t)(vv.y + pe[1]);
  vr[2] = (bf16_t)(vv.z + pe[2]); vr[3] = (bf16_t)(vv.w + pe[3]);
  *(bf16x4v*)&qo[base] = qr;
  *(bf16x4v*)&ko[base] = kr;
  *(bf16x4v*)&vo[base] = vr;
}

// ---------------------------------------------------------------------------
// Kernel 2a: singles NT GEMM, tile 128x64 (512 blocks, XCD-chunk swizzled),
// BK=32, 4 waves (2x2, each 64x32), 2-phase dbuf, all-gload_lds.
// EPI: 0 plain, 1 +bias, 2 +bias+relu
// ---------------------------------------------------------------------------
template <int EPI>
__global__ __launch_bounds__(256) void gemm_s(
    const bf16_t* __restrict__ A, const bf16_t* __restrict__ Wb,
    const float* __restrict__ bias, bf16_t* __restrict__ C) {
  constexpr int Kd = 1024, NT = Kd / 32;
  __shared__ alignas(16) bf16_t As[2][128 * 32];
  __shared__ alignas(16) bf16_t Bs[2][64 * 32];
  const int t = threadIdx.x, lane = t & 63, wid = t >> 6;
  // XCD-chunk swizzle (m204, nwg%8==0): 512 blocks = 8 XCDs x 64.
  const int bid = blockIdx.y * 16 + blockIdx.x;
  const int virt = (bid & 7) * 64 + (bid >> 3);
  const int m0 = (virt >> 4) * 128, n0 = (virt & 15) * 64;

  const bf16_t* Asrc0 = A + (size_t)(m0 + wid * 16 + (lane >> 2)) * Kd + (lane & 3) * 8;
  const bf16_t* Asrc1 = Asrc0 + (size_t)64 * Kd;
  const bf16_t* Wsrc = Wb + (size_t)(n0 + wid * 16 + (lane >> 2)) * Kd + (lane & 3) * 8;

  const f32x4 zero = {0.f, 0.f, 0.f, 0.f};
  f32x4 acc[4][2];
#pragma unroll
  for (int m = 0; m < 4; ++m) { acc[m][0] = zero; acc[m][1] = zero; }

  gload_lds16(Asrc0, &As[0][wid * 512]);
  gload_lds16(Asrc1, &As[0][2048 + wid * 512]);
  gload_lds16(Wsrc,  &Bs[0][wid * 512]);

  const int wr = wid >> 1, wc = wid & 1;
#pragma unroll 2
  for (int kt = 0; kt < NT; ++kt) {
    __syncthreads();
    const int cur = kt & 1, nxt = cur ^ 1;
    if (kt + 1 < NT) {
      const int k0 = (kt + 1) * 32;
      gload_lds16(Asrc0 + k0, &As[nxt][wid * 512]);
      gload_lds16(Asrc1 + k0, &As[nxt][2048 + wid * 512]);
      gload_lds16(Wsrc + k0,  &Bs[nxt][wid * 512]);
    }
    bf16x8 af[4], bfr[2];
#pragma unroll
    for (int m = 0; m < 4; ++m)
      af[m] = *(const bf16x8*)&As[cur][(wr * 64 + m * 16 + (lane & 15)) * 32 + (lane >> 4) * 8];
#pragma unroll
    for (int n = 0; n < 2; ++n)
      bfr[n] = *(const bf16x8*)&Bs[cur][(wc * 32 + n * 16 + (lane & 15)) * 32 + (lane >> 4) * 8];
    __builtin_amdgcn_s_setprio(1);
#pragma unroll
    for (int m = 0; m < 4; ++m)
#pragma unroll
      for (int n = 0; n < 2; ++n)
        acc[m][n] = mfma16(af[m], bfr[n], acc[m][n]);
    __builtin_amdgcn_s_setprio(0);
  }

  const int rbase = m0 + wr * 64 + (lane >> 4) * 4;
  const int cbase = n0 + wc * 32 + (lane & 15);
#pragma unroll
  for (int n = 0; n < 2; ++n) {
    const int col = cbase + n * 16;
    float bv = (EPI >= 1) ? bias[col] : 0.f;
#pragma unroll
    for (int m = 0; m < 4; ++m)
#pragma unroll
      for (int r = 0; r < 4; ++r) {
        float vv = acc[m][n][r] + bv;
        if (EPI == 2) vv = fmaxf(vv, 0.f);
        C[(size_t)(rbase + m * 16 + r) * D_ + col] = (bf16_t)vv;
      }
  }
}

// ---------------------------------------------------------------------------
// Kernel 2b: QKV batched GEMM, tile 128x128 (768 blocks, XCD-chunk swizzled),
// BK=32, 4 waves (2x2, each 64x64), 2-phase dbuf. r9-proven body.
// virt z: 0=Q, 1=K, 2=V^T out (scattered store).
// ---------------------------------------------------------------------------
__global__ __launch_bounds__(256) void gemm_qkv(
    const bf16_t* __restrict__ a0p, const bf16_t* __restrict__ a1p,
    const bf16_t* __restrict__ a2p,
    const bf16_t* __restrict__ w0p, const bf16_t* __restrict__ w1p,
    const bf16_t* __restrict__ w2p,
    bf16_t* __restrict__ o0, bf16_t* __restrict__ o1, bf16_t* __restrict__ o2) {
  constexpr int Kd = 1024, NT = Kd / 32;
  __shared__ alignas(16) bf16_t As[2][128 * 32];
  __shared__ alignas(16) bf16_t Bs[2][128 * 32];
  const int t = threadIdx.x, lane = t & 63, wid = t >> 6;
  const int g = lane >> 4, c16 = lane & 15;
  // XCD-chunk swizzle (m204, nwg%8==0): 768 blocks = 8 XCDs x 96.
  const int bid = blockIdx.z * 256 + blockIdx.y * 8 + blockIdx.x;
  const int virt = (bid & 7) * 96 + (bid >> 3);
  const int zz = virt >> 8;
  const int m0 = ((virt >> 3) & 31) * 128, n0 = (virt & 7) * 128;

  const bf16_t* A = a0p;
  const bf16_t* Wb = w0p;
  if (zz == 1) { A = a1p; Wb = w1p; }
  else if (zz == 2) { A = a2p; Wb = w2p; }

  const bf16_t* Asrc0 = A + (size_t)(m0 + wid * 16 + (lane >> 2)) * Kd + (lane & 3) * 8;
  const bf16_t* Asrc1 = Asrc0 + (size_t)64 * Kd;
  const bf16_t* Wsrc0 = Wb + (size_t)(n0 + wid * 16 + (lane >> 2)) * Kd + (lane & 3) * 8;
  const bf16_t* Wsrc1 = Wsrc0 + (size_t)64 * Kd;

  const f32x4 zero = {0.f, 0.f, 0.f, 0.f};
  f32x4 acc[4][4];
#pragma unroll
  for (int m = 0; m < 4; ++m)
#pragma unroll
    for (int n = 0; n < 4; ++n) acc[m][n] = zero;

  gload_lds16(Asrc0, &As[0][wid * 512]);
  gload_lds16(Asrc1, &As[0][2048 + wid * 512]);
  gload_lds16(Wsrc0, &Bs[0][wid * 512]);
  gload_lds16(Wsrc1, &Bs[0][2048 + wid * 512]);

  const int wr = wid >> 1, wc = wid & 1;
#pragma unroll 2
  for (int kt = 0; kt < NT; ++kt) {
    __syncthreads();
    const int cur = kt & 1, nxt = cur ^ 1;
    if (kt + 1 < NT) {
      const int k0 = (kt + 1) * 32;
      gload_lds16(Asrc0 + k0, &As[nxt][wid * 512]);
      gload_lds16(Asrc1 + k0, &As[nxt][2048 + wid * 512]);
      gload_lds16(Wsrc0 + k0, &Bs[nxt][wid * 512]);
      gload_lds16(Wsrc1 + k0, &Bs[nxt][2048 + wid * 512]);
    }
    bf16x8 af[4], bfr[4];
#pragma unroll
    for (int m = 0; m < 4; ++m)
      af[m] = *(const bf16x8*)&As[cur][(wr * 64 + m * 16 + c16) * 32 + g * 8];
#pragma unroll
    for (int n = 0; n < 4; ++n)
      bfr[n] = *(const bf16x8*)&Bs[cur][(wc * 64 + n * 16 + c16) * 32 + g * 8];
    __builtin_amdgcn_s_setprio(1);
#pragma unroll
    for (int m = 0; m < 4; ++m)
#pragma unroll
      for (int n = 0; n < 4; ++n)
        acc[m][n] = mfma16(af[m], bfr[n], acc[m][n]);
    __builtin_amdgcn_s_setprio(0);
  }

  const int rbase = m0 + wr * 64 + g * 4;
  const int cbase = n0 + wc * 64 + c16;
  if (zz == 2) {
#pragma unroll
    for (int n = 0; n < 4; ++n) {
      const int col = cbase + n * 16;
#pragma unroll
      for (int m = 0; m < 4; ++m)
#pragma unroll
        for (int r = 0; r < 4; ++r) {
          const int row = rbase + m * 16 + r;
          const int bb = row >> 11, ss = row & (S_ - 1);
          o2[(size_t)bb * D_ * S_ + (size_t)col * S_ + ss] = (bf16_t)acc[m][n][r];
        }
    }
  } else {
    bf16_t* C = (zz == 1) ? o1 : o0;
#pragma unroll
    for (int n = 0; n < 4; ++n) {
      const int col = cbase + n * 16;
#pragma unroll
      for (int m = 0; m < 4; ++m)
#pragma unroll
        for (int r = 0; r < 4; ++r)
          C[(size_t)(rbase + m * 16 + r) * D_ + col] = (bf16_t)acc[m][n][r];
    }
  }
}

// ---------------------------------------------------------------------------
// Kernel 3: flash attention, swapped-operand 32x32 MFMA, lane-local PV.
// grid (S/128, B*H), 4 waves x 32 q-rows. KVBLK=128 = TWO 64-key subtiles
// per barrier (each subtile layout/swizzle identical to the r12-proven one);
// NT=16. exp via v_exp_f32 builtin. K swap23-permuted rows; 5-bit swizzle.
// ---------------------------------------------------------------------------
__global__ __launch_bounds__(256) void attn_kernel(
    const bf16_t* __restrict__ Q, const bf16_t* __restrict__ K,
    const bf16_t* __restrict__ Vt, bf16_t* __restrict__ O) {
  constexpr int NT = S_ / 128;
  constexpr float THR = 11.5416f;          // 8 * log2(e)
  __shared__ alignas(16) bf16_t Ks[2][2][64 * 64];
  __shared__ alignas(16) bf16_t Vs[2][2][64 * 64];
  const int t = threadIdx.x, lane = t & 63, wid = t >> 6;
  const int b = blockIdx.y >> 4, h = blockIdx.y & 15;
  const int qw = blockIdx.x * 128 + wid * 32;   // this wave's 32 q-rows
  const int q31 = lane & 31, hi = lane >> 5;

  // Q as B-operand frags: col=lane&31=q, k=hi*8+j = d within 16-slice.
  bf16x8 qb[4];
  {
    const size_t qrow = (size_t)(b * S_ + qw + q31) * D_ + h * HD_ + hi * 8;
#pragma unroll
    for (int ksl = 0; ksl < 4; ++ksl) {
      bf16x8 v = *(const bf16x8*)&Q[qrow + ksl * 16];
#pragma unroll
      for (int j = 0; j < 8; ++j)
        v[j] = (bf16_t)((float)v[j] * (0.125f * 1.44269504f));
      qb[ksl] = v;
    }
  }
  bf16x8 onesb;
#pragma unroll
  for (int j = 0; j < 8; ++j) onesb[j] = (bf16_t)1.0f;

  f32x16 ctx0 = {0.f,0.f,0.f,0.f,0.f,0.f,0.f,0.f,0.f,0.f,0.f,0.f,0.f,0.f,0.f,0.f};
  f32x16 ctx1 = ctx0, lf = ctx0;
  float mrow = -1e30f;

  // 5-bit swizzle: logical slot x at row r -> phys (x ^ (r&7) ^ ((r>>3)&3))*8.
  const int srow5 = (q31 & 7) ^ ((q31 >> 3) & 3);
  int sw[4];
#pragma unroll
  for (int x = 0; x < 4; ++x) sw[x] = ((x * 2 + hi) ^ srow5) * 8;

  // staging: wave w, chunk c covers LDS tile-rows c*32 + w*8 + (lane>>3);
  // phys slot (lane&7) holds logical slot (lane&7)^s(trow).
  // K global row = swap23(LDS row) (key permutation, algebra-neutral).
  const int trow = wid * 8 + (lane >> 3);
  const int krow_g = (trow & ~12) | ((trow & 4) << 1) | ((trow & 8) >> 1);
  const int st5 = (trow & 7) ^ ((trow >> 3) & 3);
  const int lslot = ((lane & 7) ^ st5) * 8;
  const bf16_t* Ksrc0 = K + (size_t)(b * S_ + krow_g) * D_ + h * HD_ + lslot;
  const bf16_t* Ksrc1 = K + (size_t)(b * S_ + 32 + krow_g) * D_ + h * HD_ + lslot;
  const bf16_t* Vsrc0 = Vt + (size_t)b * D_ * S_ + (size_t)(h * HD_ + trow) * S_ + lslot;
  const bf16_t* Vsrc1 = Vt + (size_t)b * D_ * S_ + (size_t)(h * HD_ + 32 + trow) * S_ + lslot;

  // prologue: stage tile-pair 0 (subtiles 0 and 1)
#pragma unroll
  for (int sb = 0; sb < 2; ++sb) {
    gload_lds16(Ksrc0 + (size_t)sb * 64 * D_, &Ks[0][sb][wid * 512]);
    gload_lds16(Ksrc1 + (size_t)sb * 64 * D_, &Ks[0][sb][2048 + wid * 512]);
    gload_lds16(Vsrc0 + sb * 64, &Vs[0][sb][wid * 512]);
    gload_lds16(Vsrc1 + sb * 64, &Vs[0][sb][2048 + wid * 512]);
  }

  // one 64-key subtile: QK^T + softmax + P-pack + l/PV accumulate
  auto SUB = [&](const bf16_t* Kb, const bf16_t* Vb) {
    f32x16 s0 = {0.f,0.f,0.f,0.f,0.f,0.f,0.f,0.f,0.f,0.f,0.f,0.f,0.f,0.f,0.f,0.f};
    f32x16 s1 = s0;
    __builtin_amdgcn_s_setprio(1);
#pragma unroll
    for (int ksl = 0; ksl < 4; ++ksl) {
      bf16x8 kb0 = *(const bf16x8*)&Kb[q31 * 64 + sw[ksl]];
      bf16x8 kb1 = *(const bf16x8*)&Kb[(32 + q31) * 64 + sw[ksl]];
      s0 = mfma32(kb0, qb[ksl], s0);
      s1 = mfma32(kb1, qb[ksl], s1);
    }
    __builtin_amdgcn_s_setprio(0);

    float mt = fmaxf(s0[0], s1[0]);
#pragma unroll
    for (int r = 1; r < 16; ++r) mt = fmaxf(fmaxf(mt, s0[r]), s1[r]);
    mt = fmaxf(mt, __shfl_xor(mt, 32));
    if (__any(mt > mrow + THR)) {
      float mnew = fmaxf(mrow, mt);
      float scl = fexp2(mrow - mnew);
      mrow = mnew;
#pragma unroll
      for (int r = 0; r < 16; ++r) {
        float sc = __shfl(scl, (r & 3) + 8 * (r >> 2) + 4 * hi);
        ctx0[r] *= sc; ctx1[r] *= sc; lf[r] *= sc;
      }
    }
#pragma unroll
    for (int r = 0; r < 16; ++r) {
      s0[r] = fexp2(s0[r] - mrow);
      s1[r] = fexp2(s1[r] - mrow);
    }

    bf16x8 pa[4];
#pragma unroll
    for (int ks = 0; ks < 4; ++ks) {
      union { u32 w[4]; bf16x8 v; } u;
      if (ks < 2) {
#pragma unroll
        for (int w = 0; w < 4; ++w)
          u.w[w] = pkbf(s0[(ks & 1) * 8 + 2 * w], s0[(ks & 1) * 8 + 2 * w + 1]);
      } else {
#pragma unroll
        for (int w = 0; w < 4; ++w)
          u.w[w] = pkbf(s1[(ks & 1) * 8 + 2 * w], s1[(ks & 1) * 8 + 2 * w + 1]);
      }
      pa[ks] = u.v;
    }

    __builtin_amdgcn_s_setprio(1);
#pragma unroll
    for (int ks = 0; ks < 4; ++ks) lf = mfma32(pa[ks], onesb, lf);
#pragma unroll
    for (int ks = 0; ks < 4; ++ks) {
      bf16x8 vb0 = *(const bf16x8*)&Vb[q31 * 64 + sw[ks]];
      bf16x8 vb1 = *(const bf16x8*)&Vb[(32 + q31) * 64 + sw[ks]];
      ctx0 = mfma32(pa[ks], vb0, ctx0);
      ctx1 = mfma32(pa[ks], vb1, ctx1);
    }
    __builtin_amdgcn_s_setprio(0);
  };

  for (int kt = 0; kt < NT; ++kt) {
    __syncthreads();                       // tile-pair kt resident
    const int cur = kt & 1, nxt = cur ^ 1;
    if (kt + 1 < NT) {
      const size_t ko = (size_t)(kt + 1) * 128 * D_;
      const size_t vo = (size_t)(kt + 1) * 128;
#pragma unroll
      for (int sb = 0; sb < 2; ++sb) {
        gload_lds16(Ksrc0 + ko + (size_t)sb * 64 * D_, &Ks[nxt][sb][wid * 512]);
        gload_lds16(Ksrc1 + ko + (size_t)sb * 64 * D_, &Ks[nxt][sb][2048 + wid * 512]);
        gload_lds16(Vsrc0 + vo + sb * 64, &Vs[nxt][sb][wid * 512]);
        gload_lds16(Vsrc1 + vo + sb * 64, &Vs[nxt][sb][2048 + wid * 512]);
      }
    }
    SUB(&Ks[cur][0][0], &Vs[cur][0][0]);
    SUB(&Ks[cur][1][0], &Vs[cur][1][0]);
  }

  // epilogue: ctx D-frag row = q = crow(reg,hi), col = d = dchunk*32+(lane&31)
#pragma unroll
  for (int r = 0; r < 16; ++r) {
    const int q = (r & 3) + 8 * (r >> 2) + 4 * hi;
    const float inv = 1.f / lf[r];
    const size_t ro = (size_t)(b * S_ + qw + q) * D_ + h * HD_ + q31;
    O[ro]      = (bf16_t)(ctx0[r] * inv);
    O[ro + 32] = (bf16_t)(ctx1[r] * inv);
  }
}

// ---------------------------------------------------------------------------
// Kernel 4: out = LayerNorm(a + res) * g + b.  a,res bf16; g,b f32.
// ---------------------------------------------------------------------------
template <typename OUT>
__global__ __launch_bounds__(256) void add_ln_kernel(
    const bf16_t* __restrict__ a, const bf16_t* __restrict__ res,
    const float* __restrict__ g, const float* __restrict__ be,
    OUT* __restrict__ out) {
  const int t = threadIdx.x;
  const int d0 = t * 4;
  const size_t base = (size_t)blockIdx.x * D_ + d0;
  bf16x4v av = *(const bf16x4v*)&a[base];
  bf16x4v rv = *(const bf16x4v*)&res[base];
  float x[4];
  float s1 = 0.f, s2 = 0.f;
#pragma unroll
  for (int e = 0; e < 4; ++e) {
    x[e] = (float)av[e] + (float)rv[e];
    s1 += x[e];
    s2 += x[e] * x[e];
  }
#pragma unroll
  for (int o = 32; o > 0; o >>= 1) {
    s1 += __shfl_down(s1, o);
    s2 += __shfl_down(s2, o);
  }
  __shared__ float red[8];
  const int lane = t & 63, wid = t >> 6;
  if (lane == 0) { red[wid] = s1; red[4 + wid] = s2; }
  __syncthreads();
  if (t == 0) {
    float t1 = red[0] + red[1] + red[2] + red[3];
    float t2 = red[4] + red[5] + red[6] + red[7];
    float mu = t1 * (1.f / D_);
    float var = t2 * (1.f / D_) - mu * mu;
    red[0] = mu;
    red[1] = rsqrtf(var + 1e-5f);
  }
  __syncthreads();
  const float mu = red[0], rstd = red[1];
  const float4 gv = *(const float4*)&g[d0];
  const float4 bv = *(const float4*)&be[d0];
  float y[4];
  y[0] = (x[0] - mu) * rstd * gv.x + bv.x;
  y[1] = (x[1] - mu) * rstd * gv.y + bv.y;
  y[2] = (x[2] - mu) * rstd * gv.z + bv.z;
  y[3] = (x[3] - mu) * rstd * gv.w + bv.w;
  if constexpr (sizeof(OUT) == 2) {
    bf16x4v o;
    o[0] = (bf16_t)y[0]; o[1] = (bf16_t)y[1]; o[2] = (bf16_t)y[2]; o[3] = (bf16_t)y[3];
    *(bf16x4v*)&out[base] = o;
  } else {
    float4 o = {y[0], y[1], y[2], y[3]};
    *(float4*)&out[base] = o;
  }
}

// ---------------------------------------------------------------------------
extern "C" void kernel_launch(void* const* d_in, const int* in_sizes, int n_in,
                              void* d_out, int out_size, void* d_ws, size_t ws_size,
                              hipStream_t stream) {
  const float* key   = (const float*)d_in[0];
  const float* value = (const float*)d_in[1];
  const float* query = (const float*)d_in[2];
  const float* Wq = (const float*)d_in[3];
  const float* Wk = (const float*)d_in[4];
  const float* Wv = (const float*)d_in[5];
  const float* Wo = (const float*)d_in[6];
  const float* W1 = (const float*)d_in[7];
  const float* b1 = (const float*)d_in[8];
  const float* W2 = (const float*)d_in[9];
  const float* b2 = (const float*)d_in[10];
  const float* g1 = (const float*)d_in[11];
  const float* be1 = (const float*)d_in[12];
  const float* g2 = (const float*)d_in[13];
  const float* be2 = (const float*)d_in[14];
  float* out = (float*)d_out;

  bf16_t* ws = (bf16_t*)d_ws;
  const size_t NB = (size_t)B_ * S_ * D_;  // 4 Mi elems
  bf16_t* qpe = ws + 0 * NB;
  bf16_t* kpe = ws + 1 * NB;
  bf16_t* vpe = ws + 2 * NB;
  bf16_t* Qp  = ws + 3 * NB;
  bf16_t* Kp  = ws + 4 * NB;
  bf16_t* Vt  = ws + 5 * NB;   // [B][D][S] transposed V projection
  bf16_t* ctx = kpe;  // dead after QKV gemm
  bf16_t* ao  = vpe;  // dead after QKV gemm
  bf16_t* x1  = Qp;   // dead after attention
  bf16_t* hh  = Kp;   // dead after attention
  bf16_t* ff  = Vt;   // dead after attention

  // bf16 weights live in d_out (16 MB; 6 x 2 MB used, overwritten by final LN)
  bf16_t* wb = (bf16_t*)d_out;
  const size_t WN = (size_t)D_ * D_;
  bf16_t* Wqb = wb + 0 * WN;
  bf16_t* Wkb = wb + 1 * WN;
  bf16_t* Wvb = wb + 2 * WN;
  bf16_t* Wob = wb + 3 * WN;
  bf16_t* W1b = wb + 4 * WN;
  bf16_t* W2b = wb + 5 * WN;

  dim3 sgrid(16, 32);                          // 512 blocks (swizzled in-kernel)

  cvtw_kernel<<<dim3(D_ * D_ / 1024, 6), 256, 0, stream>>>(
      Wq, Wk, Wv, Wo, W1, W2, wb);
  addpe_kernel<<<B_ * S_, 256, 0, stream>>>(query, key, value, qpe, kpe, vpe);

  gemm_qkv<<<dim3(8, 32, 3), 256, 0, stream>>>(
      qpe, kpe, vpe, Wqb, Wkb, Wvb, Qp, Kp, Vt);

  attn_kernel<<<dim3(S_ / 128, B_ * H_), 256, 0, stream>>>(Qp, Kp, Vt, ctx);

  gemm_s<0><<<sgrid, 256, 0, stream>>>(ctx, Wob, nullptr, ao);
  add_ln_kernel<bf16_t><<<B_ * S_, 256, 0, stream>>>(ao, qpe, g1, be1, x1);

  gemm_s<2><<<sgrid, 256, 0, stream>>>(x1, W1b, b1, hh);
  gemm_s<1><<<sgrid, 256, 0, stream>>>(hh, W2b, b2, ff);
  add_ln_kernel<float><<<B_ * S_, 256, 0, stream>>>(ff, x1, g2, be2, out);
}